// Round 4
// baseline (255.003 us; speedup 1.0000x reference)
//
#include <hip/hip_runtime.h>
#include <stdint.h>

namespace {

typedef short bf16x8 __attribute__((ext_vector_type(8)));
typedef float f32x4 __attribute__((ext_vector_type(4)));
typedef unsigned short u16x4 __attribute__((ext_vector_type(4)));

constexpr int BATCH = 16;
constexpr int LQ = 2048;
constexpr int LK = 2048;
constexpr int DIM = 64;
constexpr int QB = 64;    // q rows per block (4 row-groups x 16)
constexpr int BLOCK = 512;  // 8 waves: w&3 = row-group, w>>2 = k-half
constexpr int NT = 16;      // k-tiles per half (2048 / 2 / 64)
constexpr float SCALE = 0.125f;  // 1/sqrt(64)

// LDS arena halfword offsets
constexpr int O_KHI = 0;      // [2][64*64]
constexpr int O_KLO = 8192;   // [2][64*64]
constexpr int O_VT = 16384;   // [2][64*64]
constexpr int O_PL = 24576;   // [8][16*64]
constexpr int O_MN = 32768;   // [2][64*4]  (64 rows x 8B bitmask)
constexpr int ARENA = 33280;  // 66560 B -> 2 blocks/CU

__global__ void detect_mask_dtype(const uint32_t* __restrict__ mask,
                                  int* __restrict__ flag) {
  __shared__ int bad;
  if (threadIdx.x == 0) bad = 0;
  __syncthreads();
  int my = 0;
  for (int i = threadIdx.x; i < 4096; i += 256) {
    uint32_t w = mask[i];
    if (w > 1u && w != 0x3F800000u) my = 1;
  }
  if (my) atomicOr(&bad, 1);
  __syncthreads();
  if (threadIdx.x == 0) *flag = bad;  // 1 -> uint8-packed
}

__device__ inline unsigned short f2bf(float x) {  // RNE fp32->bf16
  union { float f; unsigned u; } c;
  c.f = x;
  unsigned r = c.u + 0x7FFFu + ((c.u >> 16) & 1u);
  return (unsigned short)(r >> 16);
}
__device__ inline float bf2f(unsigned short h) {
  union { float f; unsigned u; } c;
  c.u = (unsigned)h << 16;
  return c.f;
}

// mfma_f32_16x16x32_bf16: A row m=l&15 k=(l>>4)*8+e; B col n=l&15 same k;
// C/D col n=l&15, row m=(l>>4)*4+reg.

__global__ __launch_bounds__(BLOCK, 4) void attn_mfma(
    const float* __restrict__ qp, const float* __restrict__ kp,
    const float* __restrict__ vp, const uint32_t* __restrict__ maskp,
    const int* __restrict__ flagp, float* __restrict__ out) {
  __shared__ __align__(16) unsigned short arena[ARENA];

  const int tid = threadIdx.x;
  const int w = tid >> 6;
  const int l = tid & 63;
  const int lr = l & 15;
  const int lh = l >> 4;
  const int rg = w & 3;   // row-group
  const int h = w >> 2;   // k-half (== tid>>8, so stage half == compute half)
  const int t256 = tid & 255;
  // XCD-aware bijective swizzle (512 blocks, 8 XCDs)
  const int bid = (blockIdx.x & 7) * 64 + (blockIdx.x >> 3);
  const int b = bid >> 5;
  const int qt = bid & 31;
  const int qbase = qt * QB;
  const int isU8 = *flagp;

  unsigned short* Khi = arena + O_KHI + h * 4096;
  unsigned short* Klo = arena + O_KLO + h * 4096;
  unsigned short* Vt = arena + O_VT + h * 4096;
  unsigned short* Mnb = arena + O_MN + h * 256;
  unsigned short* Pw = arena + O_PL + w * 1024;

  // ---- Q fragments (hi/lo split) ----
  bf16x8 qh[2], ql[2];
  {
    const float* qr = qp + ((size_t)b * LQ + qbase + rg * 16 + lr) * DIM;
#pragma unroll
    for (int s = 0; s < 2; ++s) {
#pragma unroll
      for (int j2 = 0; j2 < 2; ++j2) {
        float4 x = *(const float4*)(qr + s * 32 + lh * 8 + j2 * 4);
#pragma unroll
        for (int j = 0; j < 4; ++j) {
          float xv = (&x.x)[j];
          unsigned short hh = f2bf(xv);
          qh[s][j2 * 4 + j] = (short)hh;
          ql[s][j2 * 4 + j] = (short)f2bf(xv - bf2f(hh));
        }
      }
    }
  }

  // staging index precompute
  const int krow0 = t256 >> 4;       // K rows krow0+16i
  const int kd0 = (t256 & 15) * 4;   // K dim offset
  const int mrow = t256 >> 2;        // mask row (0..63)
  const int mc = t256 & 3;           // 16-col chunk within row
  const int vkq = t256 >> 4;         // V k-quad
  const int vdq = t256 & 15;         // V d-quad

  float4 pk[4];
  uint4 pm4[4];
  const uint8_t* m8 = (const uint8_t*)maskp;

  auto loadKM = [&](int kb) {
    const float* kg = kp + ((size_t)b * LK + kb) * DIM;
#pragma unroll
    for (int i = 0; i < 4; ++i)
      pk[i] = *(const float4*)(kg + (krow0 + 16 * i) * DIM + kd0);
    if (!isU8) {
      const uint32_t* mg =
          maskp + ((size_t)b * LQ + qbase + mrow) * LK + kb + mc * 16;
#pragma unroll
      for (int i = 0; i < 4; ++i) pm4[i] = *(const uint4*)(mg + i * 4);
    } else {
      pm4[0] = *(const uint4*)(m8 + ((size_t)b * LQ + qbase + mrow) * LK + kb +
                               mc * 16);
    }
  };
  loadKM(h * 1024);  // prologue prefetch t=0

  f32x4 acc_o[4];
#pragma unroll
  for (int g = 0; g < 4; ++g) acc_o[g] = (f32x4){0.f, 0.f, 0.f, 0.f};
  float den[4] = {0.f, 0.f, 0.f, 0.f};

  for (int t = 0; t < NT; ++t) {
    const int kb = h * 1024 + t * 64;
    __syncthreads();  // previous tile's LDS consumers done
    // ---- write prefetched K (hi/lo, swizzled) ----
#pragma unroll
    for (int i = 0; i < 4; ++i) {
      int row = krow0 + 16 * i;
      u16x4 khv, klv;
#pragma unroll
      for (int j = 0; j < 4; ++j) {
        float kx = (&pk[i].x)[j];
        unsigned short hh = f2bf(kx);
        khv[j] = hh;
        klv[j] = f2bf(kx - bf2f(hh));
      }
      int csw = kd0 ^ ((row & 7) << 3);
      *(u16x4*)&Khi[row * 64 + csw] = khv;
      *(u16x4*)&Klo[row * 64 + csw] = klv;
    }
    // ---- write prefetched mask bits (u16: bit j = col mc*16+j) ----
    {
      unsigned mv = 0;
      if (!isU8) {
#pragma unroll
        for (int i = 0; i < 4; ++i) {
          uint4 x = pm4[i];
          unsigned nib = (x.x != 0) | ((x.y != 0) << 1) | ((x.z != 0) << 2) |
                         ((x.w != 0) << 3);
          mv |= nib << (4 * i);
        }
      } else {
#pragma unroll
        for (int tt = 0; tt < 4; ++tt) {
          unsigned wv = (&pm4[0].x)[tt];
#pragma unroll
          for (int j = 0; j < 4; ++j)
            mv |= ((((wv >> (8 * j)) & 0xFFu) != 0u) ? 1u : 0u) << (4 * tt + j);
        }
      }
      Mnb[mrow * 4 + mc] = (unsigned short)mv;
    }
    // ---- issue next tile's K+M loads (T14: land during compute) ----
    if (t < NT - 1) loadKM(kb + 64);
    // ---- V stage (sync; covered by co-resident block) ----
    {
      const float* vg = vp + ((size_t)b * LK + kb) * DIM;
      float4 vf[4];
#pragma unroll
      for (int j = 0; j < 4; ++j)
        vf[j] = *(const float4*)(vg + (vkq * 4 + j) * DIM + vdq * 4);
      unsigned short tmp[4][4];
#pragma unroll
      for (int j = 0; j < 4; ++j)
#pragma unroll
        for (int i2 = 0; i2 < 4; ++i2) tmp[j][i2] = f2bf((&vf[j].x)[i2]);
#pragma unroll
      for (int j2 = 0; j2 < 4; ++j2) {
        u16x4 od = {tmp[0][j2], tmp[1][j2], tmp[2][j2], tmp[3][j2]};
        int d = vdq * 4 + j2;
        *(u16x4*)&Vt[d * 64 + ((vkq * 4) ^ ((d & 7) << 3))] = od;
      }
    }
    __syncthreads();  // LDS tile ready

    // ---- QK^T: S = Qhi*Khi + Qlo*Khi + Qhi*Klo ----
    f32x4 acc_s[4];
#pragma unroll
    for (int f = 0; f < 4; ++f) acc_s[f] = (f32x4){0.f, 0.f, 0.f, 0.f};
    __builtin_amdgcn_s_setprio(1);
#pragma unroll
    for (int f = 0; f < 4; ++f) {
      const int krow = f * 16 + lr;
#pragma unroll
      for (int s = 0; s < 2; ++s) {
        int csw = (s * 32 + lh * 8) ^ ((krow & 7) << 3);
        bf16x8 kh = *(const bf16x8*)&Khi[krow * 64 + csw];
        bf16x8 kl = *(const bf16x8*)&Klo[krow * 64 + csw];
        acc_s[f] =
            __builtin_amdgcn_mfma_f32_16x16x32_bf16(qh[s], kh, acc_s[f], 0, 0, 0);
        acc_s[f] =
            __builtin_amdgcn_mfma_f32_16x16x32_bf16(ql[s], kh, acc_s[f], 0, 0, 0);
        acc_s[f] =
            __builtin_amdgcn_mfma_f32_16x16x32_bf16(qh[s], kl, acc_s[f], 0, 0, 0);
      }
    }
    __builtin_amdgcn_s_setprio(0);

    // ---- mask + exp + P(bf16) ----
    unsigned long long mrows[4];
#pragma unroll
    for (int r = 0; r < 4; ++r)
      mrows[r] = *(const unsigned long long*)&Mnb[(rg * 16 + lh * 4 + r) * 4];
#pragma unroll
    for (int f = 0; f < 4; ++f) {
#pragma unroll
      for (int r = 0; r < 4; ++r) {
        int kc = f * 16 + lr;
        float e =
            ((mrows[r] >> kc) & 1ull) ? 1.0f : __expf(acc_s[f][r] * SCALE);
        den[r] += e;
        int qrow = lh * 4 + r;
        Pw[qrow * 64 + (kc ^ ((qrow & 7) << 3))] = f2bf(e);
      }
    }

    // ---- PV ----
    bf16x8 pa[2], vbf[2][4];
#pragma unroll
    for (int s2 = 0; s2 < 2; ++s2) {
      pa[s2] =
          *(const bf16x8*)&Pw[lr * 64 + ((s2 * 32 + lh * 8) ^ ((lr & 7) << 3))];
#pragma unroll
      for (int g = 0; g < 4; ++g) {
        int d = g * 16 + lr;
        vbf[s2][g] =
            *(const bf16x8*)&Vt[d * 64 + ((s2 * 32 + lh * 8) ^ ((d & 7) << 3))];
      }
    }
    __builtin_amdgcn_s_setprio(1);
#pragma unroll
    for (int s2 = 0; s2 < 2; ++s2) {
#pragma unroll
      for (int g = 0; g < 4; ++g) {
        acc_o[g] = __builtin_amdgcn_mfma_f32_16x16x32_bf16(pa[s2], vbf[s2][g],
                                                           acc_o[g], 0, 0, 0);
      }
    }
    __builtin_amdgcn_s_setprio(0);
  }

  // ---- cross-half combine (waves w and w+4 share rows) ----
  __syncthreads();  // all loop LDS traffic done; arena reusable as scratch
  float* X = (float*)arena;  // stride 24 f32 -> 16B aligned per lane
  if (h == 1) {
    float* xp = X + ((size_t)((w - 4) * 64 + l)) * 24;
#pragma unroll
    for (int g = 0; g < 4; ++g) *(f32x4*)(xp + 4 * g) = acc_o[g];
#pragma unroll
    for (int r = 0; r < 4; ++r) xp[16 + r] = den[r];
  }
  __syncthreads();
  if (h == 0) {
    float* xp = X + ((size_t)(w * 64 + l)) * 24;
#pragma unroll
    for (int g = 0; g < 4; ++g) {
      f32x4 o2 = *(const f32x4*)(xp + 4 * g);
      acc_o[g] += o2;
    }
#pragma unroll
    for (int r = 0; r < 4; ++r) den[r] += xp[16 + r];
#pragma unroll
    for (int r = 0; r < 4; ++r) {
      den[r] += __shfl_xor(den[r], 1);
      den[r] += __shfl_xor(den[r], 2);
      den[r] += __shfl_xor(den[r], 4);
      den[r] += __shfl_xor(den[r], 8);
      den[r] = 1.0f / den[r];
    }
    float* ob = out + ((size_t)b * LQ + qbase + rg * 16) * DIM;
#pragma unroll
    for (int g = 0; g < 4; ++g) {
#pragma unroll
      for (int r = 0; r < 4; ++r) {
        ob[(lh * 4 + r) * DIM + g * 16 + lr] = acc_o[g][r] * den[r];
      }
    }
  }
}

}  // namespace

extern "C" void kernel_launch(void* const* d_in, const int* in_sizes, int n_in,
                              void* d_out, int out_size, void* d_ws,
                              size_t ws_size, hipStream_t stream) {
  const float* q = (const float*)d_in[0];
  const float* k = (const float*)d_in[1];
  const float* v = (const float*)d_in[2];
  const uint32_t* mask = (const uint32_t*)d_in[3];
  float* out = (float*)d_out;
  int* flag = (int*)d_ws;

  detect_mask_dtype<<<1, 256, 0, stream>>>(mask, flag);
  attn_mfma<<<dim3(BATCH * (LQ / QB)), BLOCK, 0, stream>>>(q, k, v, mask, flag,
                                                           out);
}

// Round 5
// 129.063 us; speedup vs baseline: 1.9758x; 1.9758x over previous
//
#include <hip/hip_runtime.h>
#include <stdint.h>

namespace {

typedef short bf16x8 __attribute__((ext_vector_type(8)));
typedef float f32x4 __attribute__((ext_vector_type(4)));
typedef unsigned short u16x4 __attribute__((ext_vector_type(4)));

constexpr int BATCH = 16;
constexpr int LQ = 2048;
constexpr int LK = 2048;
constexpr int DIM = 64;
constexpr int QB = 64;      // q rows per block (4 row-groups x 16)
constexpr int BLOCK = 512;  // 8 waves: w&3 = row-group, w>>2 = k-half
constexpr int NT = 16;      // k-tiles per half (2048 / 2 / 64)
constexpr float SCALE = 0.125f;  // 1/sqrt(64)

// LDS arena halfword offsets
constexpr int O_KHI = 0;      // [2][64*64]
constexpr int O_KLO = 8192;   // [2][64*64]
constexpr int O_VT = 16384;   // [2][64*64]
constexpr int O_PL = 24576;   // [8][16*64]
constexpr int O_MN = 32768;   // [2][64*4]
constexpr int ARENA = 33280;  // 66560 B -> 2 blocks/CU (133 KB of 160 KB)

__global__ void detect_mask_dtype(const uint32_t* __restrict__ mask,
                                  int* __restrict__ flag) {
  __shared__ int bad;
  if (threadIdx.x == 0) bad = 0;
  __syncthreads();
  int my = 0;
  for (int i = threadIdx.x; i < 4096; i += 256) {
    uint32_t w = mask[i];
    if (w > 1u && w != 0x3F800000u) my = 1;
  }
  if (my) atomicOr(&bad, 1);
  __syncthreads();
  if (threadIdx.x == 0) *flag = bad;  // 1 -> uint8-packed
}

__device__ inline unsigned short f2bf(float x) {  // RNE fp32->bf16
  union { float f; unsigned u; } c;
  c.f = x;
  unsigned r = c.u + 0x7FFFu + ((c.u >> 16) & 1u);
  return (unsigned short)(r >> 16);
}
__device__ inline float bf2f(unsigned short h) {
  union { float f; unsigned u; } c;
  c.u = (unsigned)h << 16;
  return c.f;
}

// mfma_f32_16x16x32_bf16: A row m=l&15 k=(l>>4)*8+e; B col n=l&15 same k;
// C/D col n=l&15, row m=(l>>4)*4+reg.

// launch_bounds 2nd arg behaves as min BLOCKS/CU here (R4 evidence:
// (512,4) -> 32 waves/CU -> 64-VGPR cap + spills). (512,2) -> 16 waves/CU
// -> 128-VGPR cap, which is the occupancy we actually want.
__global__ __launch_bounds__(BLOCK, 2) void attn_mfma(
    const float* __restrict__ qp, const float* __restrict__ kp,
    const float* __restrict__ vp, const uint32_t* __restrict__ maskp,
    const int* __restrict__ flagp, float* __restrict__ out) {
  __shared__ __align__(16) unsigned short arena[ARENA];

  const int tid = threadIdx.x;
  const int w = tid >> 6;
  const int l = tid & 63;
  const int lr = l & 15;
  const int lh = l >> 4;
  const int rg = w & 3;  // row-group
  const int h = w >> 2;  // k-half (== tid>>8: stage half == compute half)
  const int t256 = tid & 255;
  // XCD-aware bijective swizzle (512 blocks, 8 XCDs): each XCD gets 2
  // consecutive batches -> K/V working set 2 MB < 4 MB L2.
  const int bid = (blockIdx.x & 7) * 64 + (blockIdx.x >> 3);
  const int b = bid >> 5;
  const int qt = bid & 31;
  const int qbase = qt * QB;
  const int isU8 = *flagp;

  unsigned short* Khi = arena + O_KHI + h * 4096;
  unsigned short* Klo = arena + O_KLO + h * 4096;
  unsigned short* Vt = arena + O_VT + h * 4096;
  unsigned short* Mnb = arena + O_MN + h * 256;
  unsigned short* Pw = arena + O_PL + w * 1024;

  // ---- Q fragments (hi/lo split) ----
  bf16x8 qh[2], ql[2];
  {
    const float* qr = qp + ((size_t)b * LQ + qbase + rg * 16 + lr) * DIM;
#pragma unroll
    for (int s = 0; s < 2; ++s) {
#pragma unroll
      for (int j2 = 0; j2 < 2; ++j2) {
        float4 x = *(const float4*)(qr + s * 32 + lh * 8 + j2 * 4);
#pragma unroll
        for (int j = 0; j < 4; ++j) {
          float xv = (&x.x)[j];
          unsigned short hh = f2bf(xv);
          qh[s][j2 * 4 + j] = (short)hh;
          ql[s][j2 * 4 + j] = (short)f2bf(xv - bf2f(hh));
        }
      }
    }
  }

  // staging index precompute
  const int krow0 = t256 >> 4;      // K rows krow0+16i
  const int kd0 = (t256 & 15) * 4;  // K dim offset
  const int mrow = t256 >> 2;       // mask row (0..63)
  const int mc = t256 & 3;          // 16-col chunk within row
  const int vkq = t256 >> 4;        // V k-quad
  const int vdq = t256 & 15;        // V d-quad

  float4 pk[4], pv[4];
  uint4 pm4[4];
  const uint8_t* m8 = (const uint8_t*)maskp;

  auto loadKVM = [&](int kb) {
    const float* kg = kp + ((size_t)b * LK + kb) * DIM;
    const float* vg = vp + ((size_t)b * LK + kb) * DIM;
#pragma unroll
    for (int i = 0; i < 4; ++i)
      pk[i] = *(const float4*)(kg + (krow0 + 16 * i) * DIM + kd0);
#pragma unroll
    for (int j = 0; j < 4; ++j)
      pv[j] = *(const float4*)(vg + (vkq * 4 + j) * DIM + vdq * 4);
    if (!isU8) {
      const uint32_t* mg =
          maskp + ((size_t)b * LQ + qbase + mrow) * LK + kb + mc * 16;
#pragma unroll
      for (int i = 0; i < 4; ++i) pm4[i] = *(const uint4*)(mg + i * 4);
    } else {
      pm4[0] = *(const uint4*)(m8 + ((size_t)b * LQ + qbase + mrow) * LK + kb +
                               mc * 16);
    }
  };
  loadKVM(h * 1024);  // prologue prefetch t=0

  f32x4 acc_o[4];
#pragma unroll
  for (int g = 0; g < 4; ++g) acc_o[g] = (f32x4){0.f, 0.f, 0.f, 0.f};
  float den[4] = {0.f, 0.f, 0.f, 0.f};

  for (int t = 0; t < NT; ++t) {
    const int kb = h * 1024 + t * 64;
    __syncthreads();  // previous tile's LDS consumers done
    // ---- write prefetched K (hi/lo, swizzled) ----
#pragma unroll
    for (int i = 0; i < 4; ++i) {
      int row = krow0 + 16 * i;
      u16x4 khv, klv;
#pragma unroll
      for (int j = 0; j < 4; ++j) {
        float kx = (&pk[i].x)[j];
        unsigned short hh = f2bf(kx);
        khv[j] = hh;
        klv[j] = f2bf(kx - bf2f(hh));
      }
      int csw = kd0 ^ ((row & 7) << 3);
      *(u16x4*)&Khi[row * 64 + csw] = khv;
      *(u16x4*)&Klo[row * 64 + csw] = klv;
    }
    // ---- write prefetched V (transposed 4x4, swizzled) ----
    {
      unsigned short tmp[4][4];
#pragma unroll
      for (int j = 0; j < 4; ++j)
#pragma unroll
        for (int i2 = 0; i2 < 4; ++i2) tmp[j][i2] = f2bf((&pv[j].x)[i2]);
#pragma unroll
      for (int j2 = 0; j2 < 4; ++j2) {
        u16x4 od = {tmp[0][j2], tmp[1][j2], tmp[2][j2], tmp[3][j2]};
        int d = vdq * 4 + j2;
        *(u16x4*)&Vt[d * 64 + ((vkq * 4) ^ ((d & 7) << 3))] = od;
      }
    }
    // ---- write prefetched mask bits (u16: bit j = col mc*16+j) ----
    {
      unsigned mv = 0;
      if (!isU8) {
#pragma unroll
        for (int i = 0; i < 4; ++i) {
          uint4 x = pm4[i];
          unsigned nib = (x.x != 0) | ((x.y != 0) << 1) | ((x.z != 0) << 2) |
                         ((x.w != 0) << 3);
          mv |= nib << (4 * i);
        }
      } else {
#pragma unroll
        for (int tt = 0; tt < 4; ++tt) {
          unsigned wv = (&pm4[0].x)[tt];
#pragma unroll
          for (int j = 0; j < 4; ++j)
            mv |= ((((wv >> (8 * j)) & 0xFFu) != 0u) ? 1u : 0u) << (4 * tt + j);
        }
      }
      Mnb[mrow * 4 + mc] = (unsigned short)mv;
    }
    // ---- issue next tile's loads (land during compute) ----
    if (t < NT - 1) loadKVM(kb + 64);
    __syncthreads();  // LDS tile ready

    // ---- QK^T: S = Qhi*Khi + Qlo*Khi + Qhi*Klo ----
    f32x4 acc_s[4];
#pragma unroll
    for (int f = 0; f < 4; ++f) acc_s[f] = (f32x4){0.f, 0.f, 0.f, 0.f};
    __builtin_amdgcn_s_setprio(1);
#pragma unroll
    for (int f = 0; f < 4; ++f) {
      const int krow = f * 16 + lr;
#pragma unroll
      for (int s = 0; s < 2; ++s) {
        int csw = (s * 32 + lh * 8) ^ ((krow & 7) << 3);
        bf16x8 kh = *(const bf16x8*)&Khi[krow * 64 + csw];
        bf16x8 kl = *(const bf16x8*)&Klo[krow * 64 + csw];
        acc_s[f] = __builtin_amdgcn_mfma_f32_16x16x32_bf16(qh[s], kh, acc_s[f],
                                                           0, 0, 0);
        acc_s[f] = __builtin_amdgcn_mfma_f32_16x16x32_bf16(ql[s], kh, acc_s[f],
                                                           0, 0, 0);
        acc_s[f] = __builtin_amdgcn_mfma_f32_16x16x32_bf16(qh[s], kl, acc_s[f],
                                                           0, 0, 0);
      }
    }
    __builtin_amdgcn_s_setprio(0);

    // ---- mask + exp + P(bf16) ----
    unsigned long long mrows[4];
#pragma unroll
    for (int r = 0; r < 4; ++r)
      mrows[r] = *(const unsigned long long*)&Mnb[(rg * 16 + lh * 4 + r) * 4];
#pragma unroll
    for (int f = 0; f < 4; ++f) {
#pragma unroll
      for (int r = 0; r < 4; ++r) {
        int kc = f * 16 + lr;
        float e =
            ((mrows[r] >> kc) & 1ull) ? 1.0f : __expf(acc_s[f][r] * SCALE);
        den[r] += e;
        int qrow = lh * 4 + r;
        Pw[qrow * 64 + (kc ^ ((qrow & 7) << 3))] = f2bf(e);
      }
    }

    // ---- PV (loads kept inside s2 loop to bound VGPR pressure) ----
#pragma unroll
    for (int s2 = 0; s2 < 2; ++s2) {
      bf16x8 pa =
          *(const bf16x8*)&Pw[lr * 64 + ((s2 * 32 + lh * 8) ^ ((lr & 7) << 3))];
      bf16x8 vbf[4];
#pragma unroll
      for (int g = 0; g < 4; ++g) {
        int d = g * 16 + lr;
        vbf[g] =
            *(const bf16x8*)&Vt[d * 64 + ((s2 * 32 + lh * 8) ^ ((d & 7) << 3))];
      }
      __builtin_amdgcn_s_setprio(1);
#pragma unroll
      for (int g = 0; g < 4; ++g) {
        acc_o[g] = __builtin_amdgcn_mfma_f32_16x16x32_bf16(pa, vbf[g], acc_o[g],
                                                           0, 0, 0);
      }
      __builtin_amdgcn_s_setprio(0);
      __builtin_amdgcn_sched_barrier(0);
    }
  }

  // ---- cross-half combine (waves w and w+4 share rows) ----
  __syncthreads();  // all loop LDS traffic done; arena reusable as scratch
  float* X = (float*)arena;  // stride 24 f32 -> 16B aligned per lane
  if (h == 1) {
    float* xp = X + ((size_t)((w - 4) * 64 + l)) * 24;
#pragma unroll
    for (int g = 0; g < 4; ++g) *(f32x4*)(xp + 4 * g) = acc_o[g];
#pragma unroll
    for (int r = 0; r < 4; ++r) xp[16 + r] = den[r];
  }
  __syncthreads();
  if (h == 0) {
    float* xp = X + ((size_t)(w * 64 + l)) * 24;
#pragma unroll
    for (int g = 0; g < 4; ++g) {
      f32x4 o2 = *(const f32x4*)(xp + 4 * g);
      acc_o[g] += o2;
    }
#pragma unroll
    for (int r = 0; r < 4; ++r) den[r] += xp[16 + r];
#pragma unroll
    for (int r = 0; r < 4; ++r) {
      den[r] += __shfl_xor(den[r], 1);
      den[r] += __shfl_xor(den[r], 2);
      den[r] += __shfl_xor(den[r], 4);
      den[r] += __shfl_xor(den[r], 8);
      den[r] = 1.0f / den[r];
    }
    float* ob = out + ((size_t)b * LQ + qbase + rg * 16) * DIM;
#pragma unroll
    for (int g = 0; g < 4; ++g) {
#pragma unroll
      for (int r = 0; r < 4; ++r) {
        ob[(lh * 4 + r) * DIM + g * 16 + lr] = acc_o[g][r] * den[r];
      }
    }
  }
}

}  // namespace

extern "C" void kernel_launch(void* const* d_in, const int* in_sizes, int n_in,
                              void* d_out, int out_size, void* d_ws,
                              size_t ws_size, hipStream_t stream) {
  const float* q = (const float*)d_in[0];
  const float* k = (const float*)d_in[1];
  const float* v = (const float*)d_in[2];
  const uint32_t* mask = (const uint32_t*)d_in[3];
  float* out = (float*)d_out;
  int* flag = (int*)d_ws;

  detect_mask_dtype<<<1, 256, 0, stream>>>(mask, flag);
  attn_mfma<<<dim3(BATCH * (LQ / QB)), BLOCK, 0, stream>>>(q, k, v, mask, flag,
                                                           out);
}

// Round 6
// 127.773 us; speedup vs baseline: 1.9957x; 1.0101x over previous
//
#include <hip/hip_runtime.h>
#include <stdint.h>

namespace {

typedef short bf16x8 __attribute__((ext_vector_type(8)));
typedef float f32x4 __attribute__((ext_vector_type(4)));
typedef unsigned short u16x4 __attribute__((ext_vector_type(4)));

constexpr int BATCH = 16;
constexpr int LQ = 2048;
constexpr int LK = 2048;
constexpr int DIM = 64;
constexpr int QB = 64;      // q rows per block (4 row-groups x 16)
constexpr int BLOCK = 512;  // 8 waves: w&3 = row-group, w>>2 = k-half
constexpr int NT = 16;      // k-tiles per half (2048 / 2 / 64)
constexpr float SCALE = 0.125f;  // 1/sqrt(64)

// LDS arena halfword offsets
constexpr int O_KHI = 0;      // [2][64*64]
constexpr int O_KLO = 8192;   // [2][64*64]
constexpr int O_VT = 16384;   // [2][64*64]
constexpr int O_PL = 24576;   // [8][16*64]
constexpr int O_MN = 32768;   // [2][64*4]
constexpr int ARENA = 33280;  // 66560 B -> 2 blocks/CU (133 KB of 160 KB)

// Raw workgroup barrier: orders LDS (lgkmcnt(0)) but leaves VMEM loads in
// flight (T4). __syncthreads would emit s_waitcnt vmcnt(0) and drain the
// prefetch every tile -- that drain was R5's residual stall.
__device__ inline void bar_lds() {
  asm volatile("s_waitcnt lgkmcnt(0)\n\ts_barrier" ::: "memory");
}

__global__ void detect_mask_dtype(const uint32_t* __restrict__ mask,
                                  int* __restrict__ flag) {
  __shared__ int bad;
  if (threadIdx.x == 0) bad = 0;
  __syncthreads();
  int my = 0;
  for (int i = threadIdx.x; i < 4096; i += 256) {
    uint32_t w = mask[i];
    if (w > 1u && w != 0x3F800000u) my = 1;
  }
  if (my) atomicOr(&bad, 1);
  __syncthreads();
  if (threadIdx.x == 0) *flag = bad;  // 1 -> uint8-packed
}

__device__ inline unsigned short f2bf(float x) {  // RNE fp32->bf16
  union { float f; unsigned u; } c;
  c.f = x;
  unsigned r = c.u + 0x7FFFu + ((c.u >> 16) & 1u);
  return (unsigned short)(r >> 16);
}
__device__ inline float bf2f(unsigned short h) {
  union { float f; unsigned u; } c;
  c.u = (unsigned)h << 16;
  return c.f;
}

// mfma_f32_16x16x32_bf16: A row m=l&15 k=(l>>4)*8+e; B col n=l&15 same k;
// C/D col n=l&15, row m=(l>>4)*4+reg.

// launch_bounds 2nd arg == min BLOCKS/CU here (R4 evidence: (512,4) -> 64-VGPR
// cap + 500MB spill traffic). (512,2) -> 16 waves/CU -> 128-VGPR cap.
__global__ __launch_bounds__(BLOCK, 2) void attn_mfma(
    const float* __restrict__ qp, const float* __restrict__ kp,
    const float* __restrict__ vp, const uint32_t* __restrict__ maskp,
    const int* __restrict__ flagp, float* __restrict__ out) {
  __shared__ __align__(16) unsigned short arena[ARENA];

  const int tid = threadIdx.x;
  const int w = tid >> 6;
  const int l = tid & 63;
  const int lr = l & 15;
  const int lh = l >> 4;
  const int rg = w & 3;  // row-group
  const int h = w >> 2;  // k-half (== tid>>8: stage half == compute half)
  const int t256 = tid & 255;
  // XCD-aware bijective swizzle (512 blocks, 8 XCDs): each XCD gets 2
  // consecutive batches -> K/V working set 2 MB < 4 MB L2.
  const int bid = (blockIdx.x & 7) * 64 + (blockIdx.x >> 3);
  const int b = bid >> 5;
  const int qt = bid & 31;
  const int qbase = qt * QB;
  const int isU8 = *flagp;

  unsigned short* Khi = arena + O_KHI + h * 4096;
  unsigned short* Klo = arena + O_KLO + h * 4096;
  unsigned short* Vt = arena + O_VT + h * 4096;
  unsigned short* Mnb = arena + O_MN + h * 256;
  unsigned short* Pw = arena + O_PL + w * 1024;

  // ---- Q fragments (hi/lo split) ----
  bf16x8 qh[2], ql[2];
  {
    const float* qr = qp + ((size_t)b * LQ + qbase + rg * 16 + lr) * DIM;
#pragma unroll
    for (int s = 0; s < 2; ++s) {
#pragma unroll
      for (int j2 = 0; j2 < 2; ++j2) {
        float4 x = *(const float4*)(qr + s * 32 + lh * 8 + j2 * 4);
#pragma unroll
        for (int j = 0; j < 4; ++j) {
          float xv = (&x.x)[j];
          unsigned short hh = f2bf(xv);
          qh[s][j2 * 4 + j] = (short)hh;
          ql[s][j2 * 4 + j] = (short)f2bf(xv - bf2f(hh));
        }
      }
    }
  }

  // staging index precompute
  const int krow0 = t256 >> 4;      // K rows krow0+16i
  const int kd0 = (t256 & 15) * 4;  // K dim offset
  const int mrow = t256 >> 2;       // mask row (0..63)
  const int mc = t256 & 3;          // 16-col chunk within row
  const int vkq = t256 >> 4;        // V k-quad
  const int vdq = t256 & 15;        // V d-quad

  float4 pk[4], pv[4];
  uint4 pm4[4];
  const uint8_t* m8 = (const uint8_t*)maskp;

  auto loadKVM = [&](int kb) {
    const float* kg = kp + ((size_t)b * LK + kb) * DIM;
    const float* vg = vp + ((size_t)b * LK + kb) * DIM;
#pragma unroll
    for (int i = 0; i < 4; ++i)
      pk[i] = *(const float4*)(kg + (krow0 + 16 * i) * DIM + kd0);
#pragma unroll
    for (int j = 0; j < 4; ++j)
      pv[j] = *(const float4*)(vg + (vkq * 4 + j) * DIM + vdq * 4);
    if (!isU8) {
      const uint32_t* mg =
          maskp + ((size_t)b * LQ + qbase + mrow) * LK + kb + mc * 16;
#pragma unroll
      for (int i = 0; i < 4; ++i) pm4[i] = *(const uint4*)(mg + i * 4);
    } else {
      pm4[0] = *(const uint4*)(m8 + ((size_t)b * LQ + qbase + mrow) * LK + kb +
                               mc * 16);
    }
  };
  loadKVM(h * 1024);  // prologue prefetch t=0

  f32x4 acc_o[4];
#pragma unroll
  for (int g = 0; g < 4; ++g) acc_o[g] = (f32x4){0.f, 0.f, 0.f, 0.f};
  float den[4] = {0.f, 0.f, 0.f, 0.f};

  for (int t = 0; t < NT; ++t) {
    const int kb = h * 1024 + t * 64;
    bar_lds();  // previous tile's LDS consumers done (loads stay in flight)
    // ---- write prefetched K (hi/lo, swizzled) ----
#pragma unroll
    for (int i = 0; i < 4; ++i) {
      int row = krow0 + 16 * i;
      u16x4 khv, klv;
#pragma unroll
      for (int j = 0; j < 4; ++j) {
        float kx = (&pk[i].x)[j];
        unsigned short hh = f2bf(kx);
        khv[j] = hh;
        klv[j] = f2bf(kx - bf2f(hh));
      }
      int csw = kd0 ^ ((row & 7) << 3);
      *(u16x4*)&Khi[row * 64 + csw] = khv;
      *(u16x4*)&Klo[row * 64 + csw] = klv;
    }
    // ---- write prefetched V (transposed 4x4, swizzled) ----
    {
      unsigned short tmp[4][4];
#pragma unroll
      for (int j = 0; j < 4; ++j)
#pragma unroll
        for (int i2 = 0; i2 < 4; ++i2) tmp[j][i2] = f2bf((&pv[j].x)[i2]);
#pragma unroll
      for (int j2 = 0; j2 < 4; ++j2) {
        u16x4 od = {tmp[0][j2], tmp[1][j2], tmp[2][j2], tmp[3][j2]};
        int d = vdq * 4 + j2;
        *(u16x4*)&Vt[d * 64 + ((vkq * 4) ^ ((d & 7) << 3))] = od;
      }
    }
    // ---- write prefetched mask bits (u16: bit j = col mc*16+j) ----
    {
      unsigned mv = 0;
      if (!isU8) {
#pragma unroll
        for (int i = 0; i < 4; ++i) {
          uint4 x = pm4[i];
          unsigned nib = (x.x != 0) | ((x.y != 0) << 1) | ((x.z != 0) << 2) |
                         ((x.w != 0) << 3);
          mv |= nib << (4 * i);
        }
      } else {
#pragma unroll
        for (int tt = 0; tt < 4; ++tt) {
          unsigned wv = (&pm4[0].x)[tt];
#pragma unroll
          for (int j = 0; j < 4; ++j)
            mv |= ((((wv >> (8 * j)) & 0xFFu) != 0u) ? 1u : 0u) << (4 * tt + j);
        }
      }
      Mnb[mrow * 4 + mc] = (unsigned short)mv;
    }
    // ---- issue next tile's loads; they stay in flight across bar_lds and
    //      land during this tile's compute (consumed next write phase) ----
    if (t < NT - 1) loadKVM(kb + 64);
    bar_lds();  // LDS tile ready (lgkm only -- no vmcnt drain)

    // ---- QK^T: S = Qhi*Khi + Qlo*Khi + Qhi*Klo ----
    f32x4 acc_s[4];
#pragma unroll
    for (int f = 0; f < 4; ++f) acc_s[f] = (f32x4){0.f, 0.f, 0.f, 0.f};
    __builtin_amdgcn_s_setprio(1);
#pragma unroll
    for (int f = 0; f < 4; ++f) {
      const int krow = f * 16 + lr;
#pragma unroll
      for (int s = 0; s < 2; ++s) {
        int csw = (s * 32 + lh * 8) ^ ((krow & 7) << 3);
        bf16x8 kh = *(const bf16x8*)&Khi[krow * 64 + csw];
        bf16x8 kl = *(const bf16x8*)&Klo[krow * 64 + csw];
        acc_s[f] = __builtin_amdgcn_mfma_f32_16x16x32_bf16(qh[s], kh, acc_s[f],
                                                           0, 0, 0);
        acc_s[f] = __builtin_amdgcn_mfma_f32_16x16x32_bf16(ql[s], kh, acc_s[f],
                                                           0, 0, 0);
        acc_s[f] = __builtin_amdgcn_mfma_f32_16x16x32_bf16(qh[s], kl, acc_s[f],
                                                           0, 0, 0);
      }
    }
    __builtin_amdgcn_s_setprio(0);

    // ---- mask + exp + P(bf16) ----
    unsigned long long mrows[4];
#pragma unroll
    for (int r = 0; r < 4; ++r)
      mrows[r] = *(const unsigned long long*)&Mnb[(rg * 16 + lh * 4 + r) * 4];
#pragma unroll
    for (int f = 0; f < 4; ++f) {
#pragma unroll
      for (int r = 0; r < 4; ++r) {
        int kc = f * 16 + lr;
        float e =
            ((mrows[r] >> kc) & 1ull) ? 1.0f : __expf(acc_s[f][r] * SCALE);
        den[r] += e;
        int qrow = lh * 4 + r;
        Pw[qrow * 64 + (kc ^ ((qrow & 7) << 3))] = f2bf(e);
      }
    }

    // ---- PV (loads kept inside s2 loop to bound VGPR pressure) ----
#pragma unroll
    for (int s2 = 0; s2 < 2; ++s2) {
      bf16x8 pa =
          *(const bf16x8*)&Pw[lr * 64 + ((s2 * 32 + lh * 8) ^ ((lr & 7) << 3))];
      bf16x8 vbf[4];
#pragma unroll
      for (int g = 0; g < 4; ++g) {
        int d = g * 16 + lr;
        vbf[g] =
            *(const bf16x8*)&Vt[d * 64 + ((s2 * 32 + lh * 8) ^ ((d & 7) << 3))];
      }
      __builtin_amdgcn_s_setprio(1);
#pragma unroll
      for (int g = 0; g < 4; ++g) {
        acc_o[g] = __builtin_amdgcn_mfma_f32_16x16x32_bf16(pa, vbf[g], acc_o[g],
                                                           0, 0, 0);
      }
      __builtin_amdgcn_s_setprio(0);
      __builtin_amdgcn_sched_barrier(0);
    }
  }

  // ---- cross-half combine (waves w and w+4 share rows) ----
  __syncthreads();  // epilogue: full drain is fine (no loads in flight)
  float* X = (float*)arena;  // stride 24 f32 -> 16B aligned per lane
  if (h == 1) {
    float* xp = X + ((size_t)((w - 4) * 64 + l)) * 24;
#pragma unroll
    for (int g = 0; g < 4; ++g) *(f32x4*)(xp + 4 * g) = acc_o[g];
#pragma unroll
    for (int r = 0; r < 4; ++r) xp[16 + r] = den[r];
  }
  __syncthreads();
  if (h == 0) {
    float* xp = X + ((size_t)(w * 64 + l)) * 24;
#pragma unroll
    for (int g = 0; g < 4; ++g) {
      f32x4 o2 = *(const f32x4*)(xp + 4 * g);
      acc_o[g] += o2;
    }
#pragma unroll
    for (int r = 0; r < 4; ++r) den[r] += xp[16 + r];
#pragma unroll
    for (int r = 0; r < 4; ++r) {
      den[r] += __shfl_xor(den[r], 1);
      den[r] += __shfl_xor(den[r], 2);
      den[r] += __shfl_xor(den[r], 4);
      den[r] += __shfl_xor(den[r], 8);
      den[r] = 1.0f / den[r];
    }
    float* ob = out + ((size_t)b * LQ + qbase + rg * 16) * DIM;
#pragma unroll
    for (int g = 0; g < 4; ++g) {
#pragma unroll
      for (int r = 0; r < 4; ++r) {
        ob[(lh * 4 + r) * DIM + g * 16 + lr] = acc_o[g][r] * den[r];
      }
    }
  }
}

}  // namespace

extern "C" void kernel_launch(void* const* d_in, const int* in_sizes, int n_in,
                              void* d_out, int out_size, void* d_ws,
                              size_t ws_size, hipStream_t stream) {
  const float* q = (const float*)d_in[0];
  const float* k = (const float*)d_in[1];
  const float* v = (const float*)d_in[2];
  const uint32_t* mask = (const uint32_t*)d_in[3];
  float* out = (float*)d_out;
  int* flag = (int*)d_ws;

  detect_mask_dtype<<<1, 256, 0, stream>>>(mask, flag);
  attn_mfma<<<dim3(BATCH * (LQ / QB)), BLOCK, 0, stream>>>(q, k, v, mask, flag,
                                                           out);
}